// Round 5
// baseline (722.368 us; speedup 1.0000x reference)
//
#include <hip/hip_runtime.h>

#define TSTEPS 20
#define THRESV 1.0f
#define DECAYV 0.9375f

// ws byte layout:
//   [0,      7680)   u64 s_in_bits[20][48]
//   [7680,  28160)   u64 s1_bits[20][128]
//   [28160, 48640)   u64 s2_bits[20][128]
//   [48640, 48720)   u32 cnt1[20]   (memset to 0 each launch)
//   [48720, 48800)   u32 cnt2[20]   (memset to 0 each launch)

__global__ void snn_input_kernel(const float* __restrict__ image,
                                 unsigned long long* __restrict__ s_in_bits) {
    int i = blockIdx.x * 256 + threadIdx.x;   // 0..3071
    float img = image[i];
    float mi = 0.f;
    int word = i >> 6, lane = i & 63;
    for (int t = 0; t < TSTEPS; ++t) {
        mi += img;
        bool fire = (mi >= THRESV);
        if (fire) mi -= THRESV;
        unsigned long long bm = __ballot(fire);
        if (lane == 0) s_in_bits[t * 48 + word] = bm;
    }
}

struct SMem {
    unsigned short list[8192];      // 16 KiB compacted firing-row indices
    float partials[2048];           // 8 KiB  [32 groups][64 cols]
    unsigned long long bw[128];     // snapshot of the bitmask words
    unsigned pc[128];               // per-word popcounts
    int cntp;
    float mcol[64];                 // this block's membrane slice (persistent)
};

__device__ __forceinline__ void wait_cnt(const unsigned* p, unsigned target) {
    if (threadIdx.x == 0) {
        while (__hip_atomic_load(p, __ATOMIC_ACQUIRE, __HIP_MEMORY_SCOPE_AGENT) < target)
            __builtin_amdgcn_s_sleep(16);
    }
    __syncthreads();
}

// Deterministic parallel compaction: 8 waves each own NW/8 words; ascending
// list order identical to the serial version => bitwise-identical sums.
template <int NW>
__device__ __forceinline__ int compact_par(const unsigned long long* bits, SMem& sm) {
    int tid = threadIdx.x;
    if (tid < NW) {
        unsigned long long w = __hip_atomic_load(&bits[tid], __ATOMIC_RELAXED, __HIP_MEMORY_SCOPE_AGENT);
        sm.bw[tid] = w;
        sm.pc[tid] = (unsigned)__popcll(w);
    }
    __syncthreads();
    constexpr int WPW = NW / 8;
    int wave = tid >> 6, lane = tid & 63;
    int w0 = wave * WPW;
    int base = 0;
    for (int i = lane; i < w0; i += 64) base += (int)sm.pc[i];
    #pragma unroll
    for (int off = 1; off < 64; off <<= 1) base += __shfl_xor(base, off);
    if (wave == 0) {
        int tot = 0;
        for (int i = lane; i < NW; i += 64) tot += (int)sm.pc[i];
        #pragma unroll
        for (int off = 1; off < 64; off <<= 1) tot += __shfl_xor(tot, off);
        if (lane == 0) sm.cntp = tot;
    }
    for (int i = 0; i < WPW; ++i) {
        unsigned long long w = sm.bw[w0 + i];
        if ((w >> lane) & 1ull) {
            int pos = base + __popcll(w & ((1ull << lane) - 1ull));
            sm.list[pos] = (unsigned short)(((w0 + i) << 6) + lane);
        }
        base += __popcll(w);
    }
    __syncthreads();
    return sm.cntp;
}

// 64-column gather + LIF epilogue. 8-deep explicit pipeline: 8 x float4 in
// flight per wave (64 KB/CU). Per-thread FP-add order is the same ascending-k
// chain as the round-2 kernel => bitwise-identical sums.
__device__ __forceinline__ void gather_lif64(const float* __restrict__ W, int colbase,
                                             int count, SMem& sm,
                                             unsigned long long* dst_word,
                                             unsigned* cnt_pub) {
    int tid = threadIdx.x;
    const float4* Wc = (const float4*)(W + (size_t)colbase) + (tid & 15);
    float ax = 0.f, ay = 0.f, az = 0.f, aw = 0.f;
    int k = tid >> 4;
    for (; k + 224 < count; k += 256) {              // 8 x 16B loads in flight
        float4 a0 = Wc[(size_t)sm.list[k]       * 2048];
        float4 a1 = Wc[(size_t)sm.list[k + 32]  * 2048];
        float4 a2 = Wc[(size_t)sm.list[k + 64]  * 2048];
        float4 a3 = Wc[(size_t)sm.list[k + 96]  * 2048];
        float4 a4 = Wc[(size_t)sm.list[k + 128] * 2048];
        float4 a5 = Wc[(size_t)sm.list[k + 160] * 2048];
        float4 a6 = Wc[(size_t)sm.list[k + 192] * 2048];
        float4 a7 = Wc[(size_t)sm.list[k + 224] * 2048];
        ax += a0.x; ay += a0.y; az += a0.z; aw += a0.w;
        ax += a1.x; ay += a1.y; az += a1.z; aw += a1.w;
        ax += a2.x; ay += a2.y; az += a2.z; aw += a2.w;
        ax += a3.x; ay += a3.y; az += a3.z; aw += a3.w;
        ax += a4.x; ay += a4.y; az += a4.z; aw += a4.w;
        ax += a5.x; ay += a5.y; az += a5.z; aw += a5.w;
        ax += a6.x; ay += a6.y; az += a6.z; aw += a6.w;
        ax += a7.x; ay += a7.y; az += a7.z; aw += a7.w;
    }
    for (; k + 96 < count; k += 128) {               // 4-deep mid tail
        float4 a0 = Wc[(size_t)sm.list[k]      * 2048];
        float4 a1 = Wc[(size_t)sm.list[k + 32] * 2048];
        float4 a2 = Wc[(size_t)sm.list[k + 64] * 2048];
        float4 a3 = Wc[(size_t)sm.list[k + 96] * 2048];
        ax += a0.x; ay += a0.y; az += a0.z; aw += a0.w;
        ax += a1.x; ay += a1.y; az += a1.z; aw += a1.w;
        ax += a2.x; ay += a2.y; az += a2.z; aw += a2.w;
        ax += a3.x; ay += a3.y; az += a3.z; aw += a3.w;
    }
    for (; k < count; k += 32) {
        float4 a = Wc[(size_t)sm.list[k] * 2048];
        ax += a.x; ay += a.y; az += a.z; aw += a.w;
    }
    ((float4*)sm.partials)[(tid >> 4) * 16 + (tid & 15)] = make_float4(ax, ay, az, aw);
    __syncthreads();

    if (tid < 64) {
        float s = 0.f;
        #pragma unroll
        for (int gg = 0; gg < 32; ++gg) s += sm.partials[gg * 64 + tid];
        float v = sm.mcol[tid] + s;
        bool fire = (v >= THRESV);
        if (fire) v -= THRESV;
        sm.mcol[tid] = fire ? v : v * DECAYV;
        unsigned long long bm = __ballot(fire);
        if (tid == 0) {
            __hip_atomic_store(dst_word, bm, __ATOMIC_RELEASE, __HIP_MEMORY_SCOPE_AGENT);
            __hip_atomic_fetch_add(cnt_pub, 1u, __ATOMIC_RELEASE, __HIP_MEMORY_SCOPE_AGENT);
        }
    }
}

__global__ void
snn_persistent(const float* __restrict__ W1, const float* __restrict__ W2,
               const float* __restrict__ W3,
               const unsigned long long* __restrict__ s_in_bits,
               unsigned long long* __restrict__ s1_bits,
               unsigned long long* __restrict__ s2_bits,
               unsigned* __restrict__ cnt1, unsigned* __restrict__ cnt2,
               float* __restrict__ out) {
    __shared__ __align__(16) SMem sm;
    int tid = threadIdx.x;
    int b = blockIdx.x;
    if (tid < 64) sm.mcol[tid] = 0.f;   // wave 0 writes, wave 0 reads later

    if (b < 128) {
        // ---- layer-1 role: depends only on precomputed input spikes ----
        for (int t = 0; t < TSTEPS; ++t) {
            int count = compact_par<48>(s_in_bits + (size_t)t * 48, sm);
            gather_lif64(W1, b * 64, count, sm, &s1_bits[t * 128 + b], &cnt1[t]);
        }
    } else if (b < 256) {
        // ---- layer-2 role: consumes s1[t-1] ----
        int cb = b - 128;
        if (tid == 0) {   // step 0: zero input -> no fire, membrane stays 0
            __hip_atomic_store(&s2_bits[cb], 0ull, __ATOMIC_RELEASE, __HIP_MEMORY_SCOPE_AGENT);
            __hip_atomic_fetch_add(&cnt2[0], 1u, __ATOMIC_RELEASE, __HIP_MEMORY_SCOPE_AGENT);
        }
        for (int t = 1; t < TSTEPS; ++t) {
            wait_cnt(&cnt1[t - 1], 128);
            int count = compact_par<128>(s1_bits + (size_t)(t - 1) * 128, sm);
            gather_lif64(W2, cb * 64, count, sm, &s2_bits[t * 128 + cb], &cnt2[t]);
        }
    } else {
        // ---- layer-3 role (single block): consumes s2[t-1] ----
        if (tid < 10) { out[tid] = 0.f; out[10 + tid] = 0.f; }  // rows 0,1
        for (int t = 1; t < TSTEPS; ++t) {
            wait_cnt(&cnt2[t - 1], 128);
            int count = compact_par<128>(s2_bits + (size_t)(t - 1) * 128, sm);
            int col = tid & 15, g = tid >> 4;                    // 32 groups
            float acc = 0.f;
            if (col < 10) {
                for (int k = g; k < count; k += 32)
                    acc += W3[(size_t)sm.list[k] * 10 + col];
            }
            sm.partials[g * 16 + col] = acc;
            __syncthreads();
            if (tid < 10) {
                float s = 0.f;
                for (int gg = 0; gg < 32; ++gg) s += sm.partials[gg * 16 + tid];
                float v = sm.mcol[tid] + s;
                bool fire = (v >= THRESV);
                if (fire) v -= THRESV;
                sm.mcol[tid] = fire ? v : v * DECAYV;
                out[(t + 1) * 10 + tid] = fire ? 1.f : 0.f;
            }
            __syncthreads();
        }
    }
}

extern "C" void kernel_launch(void* const* d_in, const int* in_sizes, int n_in,
                              void* d_out, int out_size, void* d_ws, size_t ws_size,
                              hipStream_t stream) {
    const float* image = (const float*)d_in[0];
    const float* W1 = (const float*)d_in[1];
    const float* W2 = (const float*)d_in[2];
    const float* W3 = (const float*)d_in[3];
    float* out = (float*)d_out;

    char* ws = (char*)d_ws;
    unsigned long long* s_in_bits = (unsigned long long*)ws;            // [20][48]
    unsigned long long* s1_bits = (unsigned long long*)(ws + 7680);     // [20][128]
    unsigned long long* s2_bits = (unsigned long long*)(ws + 28160);    // [20][128]
    unsigned* cnt1 = (unsigned*)(ws + 48640);                           // [20]
    unsigned* cnt2 = (unsigned*)(ws + 48720);                           // [20]

    // counters must be zero before the persistent kernel starts (each replay)
    hipMemsetAsync(ws + 48640, 0, 160, stream);

    snn_input_kernel<<<12, 256, 0, stream>>>(image, s_in_bits);

    snn_persistent<<<257, 512, 0, stream>>>(W1, W2, W3, s_in_bits,
                                            s1_bits, s2_bits, cnt1, cnt2, out);
}